// Round 2
// baseline (539.679 us; speedup 1.0000x reference)
//
#include <hip/hip_runtime.h>

// AbstractConv3D: 16 dense R^3 levels, 3x3x3 conv, C_in=C_out=16, B=2, fp32 I/O.
// Round 4: attack block-granularity latency. Tile 4x4x16 -> 8x4x16:
//   - 512 threads (8 waves, wave = x-slice dx=0..7), halo 10x6x18 = 1080 voxels,
//     LDS 51,840 B -> 3 blocks/CU = 24 waves/CU (75% occupancy, was 52%).
//   - halo read-amplification 2.53x -> 2.11x (17% less staging work/voxel).
//   - 8,250 blocks (was 16,088): half the geometry/level-decode/barrier overhead.
//   - __launch_bounds__(512, 6): 6 waves/EU = 3 blocks/CU; VGPR cap 85 (use ~48).
// Carried from round 3 (all verified): pack_weights one-shot per-lane bf16
// B-fragments in d_ws (14 coalesced dwordx4/lane in main kernel);
// v_cvt_pk_bf16_f32 staging; compile-time tap geometry; 48 B voxel stride
// (16 bf16 + 8 pad shorts -> conflict-free b128); 14x mfma_16x16x32_bf16 per
// z-run (28th tap zero-weighted, A-addr clamped to tap 26); D: col=c_out,
// row=quad*4+reg=z.

#define NLEV 16
#define NTOT 1844282

typedef short  short8 __attribute__((ext_vector_type(8)));
typedef float  f32x4  __attribute__((ext_vector_type(4)));
typedef unsigned int u32x4 __attribute__((ext_vector_type(4)));

__constant__ int c_res[NLEV]  = {16,18,20,22,24,27,30,34,38,42,47,52,58,64,72,80};
__constant__ int c_voff[NLEV] = {0,4096,9928,17928,28576,42400,62083,89083,
                                 128387,183259,257347,361170,501778,696890,
                                 959034,1332282};
// tiles per level: ceil(R/8)*ceil(R/4)*ceil(R/16), cumulative
__constant__ int c_tblk[NLEV+1] = {0,8,38,68,104,140,196,260,395,545,743,959,
                                   1323,1803,2315,3125,4125};
__constant__ int c_ntz[NLEV] = {1,2,2,2,2,2,2,3,3,3,3,4,4,4,5,5};
__constant__ int c_nty[NLEV] = {4,5,5,6,6,7,8,9,10,11,12,13,15,16,18,20};

__device__ __forceinline__ unsigned short f2bf(float f) {
    union { float f; unsigned int u; } v; v.f = f;
    unsigned int u = v.u;
    return (unsigned short)((u + 0x7FFFu + ((u >> 16) & 1u)) >> 16);
}

// HW packed f32->bf16 (RNE).
__device__ __forceinline__ unsigned int cvt_pk_bf16(float lo, float hi) {
    unsigned int r;
    asm("v_cvt_pk_bf16_f32 %0, %1, %2" : "=v"(r) : "v"(lo), "v"(hi));
    return r;
}

// LDS geometry (in shorts) of tap t, clamped to 26 for the padded tap.
constexpr int geo24(int t) {
    int ta = t > 26 ? 26 : t;
    int kd = ta / 9, rr = ta - kd * 9, kh = rr / 3, kw = rr - kh * 3;
    return ((kd * 6 + kh) * 18 + kw) * 24;
}

__device__ __forceinline__ short8 lds_load8(const short* p) {
    return *reinterpret_cast<const short8*>(__builtin_assume_aligned(p, 16));
}

// ---- one-shot: per-lane bf16 B-fragments -> wbuf[l][i][lane][8] (229,376 B) ----
__global__ void pack_weights(const float* __restrict__ w,
                             unsigned short* __restrict__ wbuf) {
    const int l = blockIdx.x;
    const float* wlev = w + l * 6912;                 // 27*16*16
    for (int task = threadIdx.x; task < 14 * 64; task += blockDim.x) {
        const int i    = task >> 6;                   // tap pair 0..13
        const int lane = task & 63;
        const int quad = lane >> 4;
        const int m    = lane & 15;                   // c_out
        const int h8   = (quad & 1) * 8;              // ci half
        const int qh   = quad >> 1;                   // tap parity
        const int t    = 2 * i + qh;                  // tap 0..27
        short8 v;
        if (t < 27) {
            const float* wp = wlev + t * 256 + h8 * 16 + m;
#pragma unroll
            for (int j = 0; j < 8; ++j) v[j] = (short)f2bf(wp[j * 16]);
        } else {
#pragma unroll
            for (int j = 0; j < 8; ++j) v[j] = 0;     // zero-weighted pad tap
        }
        *reinterpret_cast<short8*>(wbuf + l * 7168 + task * 8) = v;
    }
}

__global__ __launch_bounds__(512, 6)
void conv3d_mfma_kernel(const float* __restrict__ in,
                        const unsigned short* __restrict__ wbuf,
                        const float* __restrict__ bias,
                        float* __restrict__ out) {
    // 1080 halo voxels (10x6x18) * 24 shorts (16 data + 8 pad) = 51,840 B
    __shared__ __align__(16) short s_in[1080 * 24];

    const int bid = blockIdx.x;
    const int b   = blockIdx.y;

    int l = 0;
#pragma unroll
    for (int i = 1; i < NLEV; ++i) l += (bid >= c_tblk[i]);

    const int R    = c_res[l];
    const int voff = c_voff[l];
    const int ntz  = c_ntz[l];
    const int nty  = c_nty[l];

    const int local = bid - c_tblk[l];
    const int tz = local % ntz;
    const int t2 = local / ntz;
    const int ty = t2 % nty;
    const int tx = t2 / nty;

    const float* inb  = in  + ((long long)b * NTOT + voff) * 16;
    float*       outb = out + ((long long)b * NTOT + voff) * 16;

    // ---- stage halo tile (10 x 6 x 18) into LDS as bf16, zeros outside ----
    for (int h = threadIdx.x; h < 1080; h += 512) {
        const int hz = h % 18;
        const int t  = h / 18;
        const int hy = t % 6;
        const int hx = t / 6;
        const int gx = tx * 8 - 1 + hx;
        const int gy = ty * 4 - 1 + hy;
        const int gz = tz * 16 - 1 + hz;
        const bool ok = ((unsigned)gx < (unsigned)R) &
                        ((unsigned)gy < (unsigned)R) &
                        ((unsigned)gz < (unsigned)R);
        u32x4 lo = {0u, 0u, 0u, 0u}, hi = {0u, 0u, 0u, 0u};
        if (ok) {
            const f32x4* ip = reinterpret_cast<const f32x4*>(
                inb + (long long)(((gx * R + gy) * R + gz) * 16));
            f32x4 q0 = ip[0], q1 = ip[1], q2 = ip[2], q3 = ip[3];
            lo[0] = cvt_pk_bf16(q0[0], q0[1]);
            lo[1] = cvt_pk_bf16(q0[2], q0[3]);
            lo[2] = cvt_pk_bf16(q1[0], q1[1]);
            lo[3] = cvt_pk_bf16(q1[2], q1[3]);
            hi[0] = cvt_pk_bf16(q2[0], q2[1]);
            hi[1] = cvt_pk_bf16(q2[2], q2[3]);
            hi[2] = cvt_pk_bf16(q3[0], q3[1]);
            hi[3] = cvt_pk_bf16(q3[2], q3[3]);
        }
        *reinterpret_cast<u32x4*>(&s_in[h * 24])     = lo;
        *reinterpret_cast<u32x4*>(&s_in[h * 24 + 8]) = hi;
    }

    // ---- per-lane geometry + prepacked weight fragments (in flight over barrier) ----
    const int lane = threadIdx.x & 63;
    const int wv   = threadIdx.x >> 6;     // wave id = dx (0..7)
    const int quad = lane >> 4;
    const int m    = lane & 15;            // A-row (z) / D-col (c_out)
    const int co   = m;
    const int h8   = (quad & 1) * 8;       // ci half
    const int qh   = quad >> 1;            // tap parity

    const float bv = bias[l * 16 + co];

    // 14 coalesced 16 B loads per lane; level fragment block is 14.3 KB (L2-hit).
    short8 wf[14];
    const short8* wp8 = reinterpret_cast<const short8*>(wbuf) + l * 896 + lane;
#pragma unroll
    for (int i = 0; i < 14; ++i) wf[i] = wp8[i * 64];

    // LDS A-offsets: compile-time constants per (i,qh), + per-lane base.
    const int mbase = m * 24 + h8;
    int ofs[14];
#pragma unroll
    for (int i = 0; i < 14; ++i)
        ofs[i] = (qh ? geo24(2 * i + 1) : geo24(2 * i)) + mbase;

    __syncthreads();

    // ---- compute: wave = x-slice dx=wv; 4 z-runs (dy=0..3) of 16 voxels ----
    const int gx = tx * 8 + wv;
    if (gx < R) {
        const int pb0 = wv * 2592;          // (dx*6)*18*24
#pragma unroll
        for (int j = 0; j < 4; ++j) {
            const int gy = ty * 4 + j;
            if (gy < R) {
                f32x4 acc = {bv, bv, bv, bv};
                const int pb = pb0 + j * 432;   // + dy*18*24
#pragma unroll
                for (int i = 0; i < 14; ++i) {
                    short8 a = lds_load8(&s_in[pb + ofs[i]]);
                    acc = __builtin_amdgcn_mfma_f32_16x16x32_bf16(a, wf[i], acc, 0, 0, 0);
                }
                float* ob = outb + (long long)(gx * R + gy) * R * 16 + co;
                const int gz0 = tz * 16 + quad * 4;
#pragma unroll
                for (int r = 0; r < 4; ++r) {
                    const int gz = gz0 + r;
                    if (gz < R) ob[(long long)gz * 16] = acc[r];
                }
            }
        }
    }
}

extern "C" void kernel_launch(void* const* d_in, const int* in_sizes, int n_in,
                              void* d_out, int out_size, void* d_ws, size_t ws_size,
                              hipStream_t stream) {
    const float* in   = (const float*)d_in[0];   // (B, N, 16) fp32
    const float* w    = (const float*)d_in[1];   // (16, 3,3,3, 16, 16) fp32
    const float* bias = (const float*)d_in[2];   // (16, 16) fp32
    float* out = (float*)d_out;                  // (B, N, 16) fp32
    unsigned short* wbuf = (unsigned short*)d_ws; // uses 229,376 B of workspace

    pack_weights<<<dim3(NLEV), 256, 0, stream>>>(w, wbuf);
    dim3 grid(4125, 2);
    conv3d_mfma_kernel<<<grid, 512, 0, stream>>>(in, wbuf, bias, out);
}

// Round 3
// 436.863 us; speedup vs baseline: 1.2353x; 1.2353x over previous
//
#include <hip/hip_runtime.h>

// AbstractConv3D: 16 dense R^3 levels, 3x3x3 conv, C_in=C_out=16, B=2, fp32 I/O.
// Round 5: revert the 512-thread experiment (register spills: WRITE_SIZE
// 230->431 MB at VGPR cap 85). Back to 4x4x16 / 256 threads, plus:
//   - loop-swap compute: tap i outer, dy j inner, 4 live accumulators.
//     wf[i] is live only within its i-iteration -> no spill pressure, each
//     fragment loaded exactly once from L2 (round 3's VGPR=48 showed the
//     compiler was rematerializing wf loads inside the j-loop).
//     Inner 4 LDS reads share one base -> ds_read offset: immediates.
//   - __launch_bounds__(256,5): 5 blocks/CU (LDS 5*31,232 = 156,160 <= 163,840
//     exact fit; VGPR cap ~96 >= ~70 need). Occupancy 52% -> 62.5% to raise
//     achieved HBM BW (round 3 was throughput-limited at 3.1 of 6.3 TB/s).
// Carried (verified): pack_weights one-shot per-lane bf16 B-fragments in d_ws;
// v_cvt_pk_bf16_f32 staging; compile-time tap geometry; 48 B voxel stride
// (16 bf16 + 8 pad shorts -> conflict-free b128); 14x mfma_16x16x32_bf16
// (28th tap zero-weighted, A-addr clamped to tap 26); D: col=c_out,
// row=quad*4+reg=z; wave = x-slice.

#define NLEV 16
#define NTOT 1844282

typedef short  short8 __attribute__((ext_vector_type(8)));
typedef float  f32x4  __attribute__((ext_vector_type(4)));
typedef unsigned int u32x4 __attribute__((ext_vector_type(4)));

__constant__ int c_res[NLEV]  = {16,18,20,22,24,27,30,34,38,42,47,52,58,64,72,80};
__constant__ int c_voff[NLEV] = {0,4096,9928,17928,28576,42400,62083,89083,
                                 128387,183259,257347,361170,501778,696890,
                                 959034,1332282};
// tiles per level: ceil(R/4)^2 * ceil(R/16), cumulative
__constant__ int c_tblk[NLEV+1] = {0,16,66,116,188,260,358,486,729,1029,1392,
                                   1824,2500,3400,4424,6044,8044};
__constant__ int c_ntz[NLEV] = {1,2,2,2,2,2,2,3,3,3,3,4,4,4,5,5};
__constant__ int c_nty[NLEV] = {4,5,5,6,6,7,8,9,10,11,12,13,15,16,18,20};

__device__ __forceinline__ unsigned short f2bf(float f) {
    union { float f; unsigned int u; } v; v.f = f;
    unsigned int u = v.u;
    return (unsigned short)((u + 0x7FFFu + ((u >> 16) & 1u)) >> 16);
}

// HW packed f32->bf16 (RNE).
__device__ __forceinline__ unsigned int cvt_pk_bf16(float lo, float hi) {
    unsigned int r;
    asm("v_cvt_pk_bf16_f32 %0, %1, %2" : "=v"(r) : "v"(lo), "v"(hi));
    return r;
}

// LDS geometry (in shorts) of tap t, clamped to 26 for the padded tap.
constexpr int geo24(int t) {
    int ta = t > 26 ? 26 : t;
    int kd = ta / 9, rr = ta - kd * 9, kh = rr / 3, kw = rr - kh * 3;
    return ((kd * 6 + kh) * 18 + kw) * 24;
}

__device__ __forceinline__ short8 lds_load8(const short* p) {
    return *reinterpret_cast<const short8*>(__builtin_assume_aligned(p, 16));
}

// ---- one-shot: per-lane bf16 B-fragments -> wbuf[l][i][lane][8] (229,376 B) ----
__global__ void pack_weights(const float* __restrict__ w,
                             unsigned short* __restrict__ wbuf) {
    const int l = blockIdx.x;
    const float* wlev = w + l * 6912;                 // 27*16*16
    for (int task = threadIdx.x; task < 14 * 64; task += blockDim.x) {
        const int i    = task >> 6;                   // tap pair 0..13
        const int lane = task & 63;
        const int quad = lane >> 4;
        const int m    = lane & 15;                   // c_out
        const int h8   = (quad & 1) * 8;              // ci half
        const int qh   = quad >> 1;                   // tap parity
        const int t    = 2 * i + qh;                  // tap 0..27
        short8 v;
        if (t < 27) {
            const float* wp = wlev + t * 256 + h8 * 16 + m;
#pragma unroll
            for (int j = 0; j < 8; ++j) v[j] = (short)f2bf(wp[j * 16]);
        } else {
#pragma unroll
            for (int j = 0; j < 8; ++j) v[j] = 0;     // zero-weighted pad tap
        }
        *reinterpret_cast<short8*>(wbuf + l * 7168 + task * 8) = v;
    }
}

__global__ __launch_bounds__(256, 5)
void conv3d_mfma_kernel(const float* __restrict__ in,
                        const unsigned short* __restrict__ wbuf,
                        const float* __restrict__ bias,
                        float* __restrict__ out) {
    // 648 halo voxels (6x6x18) * 24 shorts (16 data + 8 pad) = 31,104 B
    __shared__ __align__(16) short s_in[648 * 24];

    const int bid = blockIdx.x;
    const int b   = blockIdx.y;

    int l = 0;
#pragma unroll
    for (int i = 1; i < NLEV; ++i) l += (bid >= c_tblk[i]);

    const int R    = c_res[l];
    const int voff = c_voff[l];
    const int ntz  = c_ntz[l];
    const int nty  = c_nty[l];

    const int local = bid - c_tblk[l];
    const int tz = local % ntz;
    const int t2 = local / ntz;
    const int ty = t2 % nty;
    const int tx = t2 / nty;

    const float* inb  = in  + ((long long)b * NTOT + voff) * 16;
    float*       outb = out + ((long long)b * NTOT + voff) * 16;

    // ---- stage halo tile (6 x 6 x 18) into LDS as bf16, zeros outside ----
    for (int h = threadIdx.x; h < 648; h += 256) {
        const int hz = h % 18;
        const int t  = h / 18;
        const int hy = t % 6;
        const int hx = t / 6;
        const int gx = tx * 4 - 1 + hx;
        const int gy = ty * 4 - 1 + hy;
        const int gz = tz * 16 - 1 + hz;
        const bool ok = ((unsigned)gx < (unsigned)R) &
                        ((unsigned)gy < (unsigned)R) &
                        ((unsigned)gz < (unsigned)R);
        u32x4 lo = {0u, 0u, 0u, 0u}, hi = {0u, 0u, 0u, 0u};
        if (ok) {
            const f32x4* ip = reinterpret_cast<const f32x4*>(
                inb + (long long)(((gx * R + gy) * R + gz) * 16));
            f32x4 q0 = ip[0], q1 = ip[1], q2 = ip[2], q3 = ip[3];
            lo[0] = cvt_pk_bf16(q0[0], q0[1]);
            lo[1] = cvt_pk_bf16(q0[2], q0[3]);
            lo[2] = cvt_pk_bf16(q1[0], q1[1]);
            lo[3] = cvt_pk_bf16(q1[2], q1[3]);
            hi[0] = cvt_pk_bf16(q2[0], q2[1]);
            hi[1] = cvt_pk_bf16(q2[2], q2[3]);
            hi[2] = cvt_pk_bf16(q3[0], q3[1]);
            hi[3] = cvt_pk_bf16(q3[2], q3[3]);
        }
        *reinterpret_cast<u32x4*>(&s_in[h * 24])     = lo;
        *reinterpret_cast<u32x4*>(&s_in[h * 24 + 8]) = hi;
    }

    // ---- per-lane geometry (fragments loaded lazily in the i-loop) ----
    const int lane = threadIdx.x & 63;
    const int wv   = threadIdx.x >> 6;     // wave id = dx (0..3)
    const int quad = lane >> 4;
    const int m    = lane & 15;            // A-row (z) / D-col (c_out)
    const int co   = m;
    const int h8   = (quad & 1) * 8;       // ci half
    const int qh   = quad >> 1;            // tap parity

    const float bv = bias[l * 16 + co];

    const short8* wp8 = reinterpret_cast<const short8*>(wbuf) + l * 896 + lane;

    // LDS A-offsets: compile-time constants per (i,qh), + per-lane base.
    const int mbase = m * 24 + h8;
    int ofs[14];
#pragma unroll
    for (int i = 0; i < 14; ++i)
        ofs[i] = (qh ? geo24(2 * i + 1) : geo24(2 * i)) + mbase;

    __syncthreads();

    // ---- compute: wave = x-slice dx=wv; tap-outer loop, 4 dy accumulators ----
    const int gx = tx * 4 + wv;
    if (gx < R) {
        const int pb0 = wv * 2592;          // (dx*6)*18*24
        f32x4 acc[4];
#pragma unroll
        for (int j = 0; j < 4; ++j) acc[j] = {bv, bv, bv, bv};

#pragma unroll
        for (int i = 0; i < 14; ++i) {
            const short8 wfi = wp8[i * 64];           // one 16 B L2-hit load
            const int base = pb0 + ofs[i];
#pragma unroll
            for (int j = 0; j < 4; ++j) {             // +j*432 shorts = imm offs
                short8 a = lds_load8(&s_in[base + j * 432]);
                acc[j] = __builtin_amdgcn_mfma_f32_16x16x32_bf16(a, wfi, acc[j], 0, 0, 0);
            }
        }

        const int gz0 = tz * 16 + quad * 4;
#pragma unroll
        for (int j = 0; j < 4; ++j) {
            const int gy = ty * 4 + j;
            if (gy < R) {
                float* ob = outb + (long long)(gx * R + gy) * R * 16 + co;
#pragma unroll
                for (int r = 0; r < 4; ++r) {
                    const int gz = gz0 + r;
                    if (gz < R) ob[(long long)gz * 16] = acc[j][r];
                }
            }
        }
    }
}

extern "C" void kernel_launch(void* const* d_in, const int* in_sizes, int n_in,
                              void* d_out, int out_size, void* d_ws, size_t ws_size,
                              hipStream_t stream) {
    const float* in   = (const float*)d_in[0];   // (B, N, 16) fp32
    const float* w    = (const float*)d_in[1];   // (16, 3,3,3, 16, 16) fp32
    const float* bias = (const float*)d_in[2];   // (16, 16) fp32
    float* out = (float*)d_out;                  // (B, N, 16) fp32
    unsigned short* wbuf = (unsigned short*)d_ws; // uses 229,376 B of workspace

    pack_weights<<<dim3(NLEV), 256, 0, stream>>>(w, wbuf);
    dim3 grid(8044, 2);
    conv3d_mfma_kernel<<<grid, 256, 0, stream>>>(in, wbuf, bias, out);
}